// Round 3
// baseline (4704.156 us; speedup 1.0000x reference)
//
#include <hip/hip_runtime.h>

#define N_NODES   100000
#define N_EDGES   1600000
#define CH        64
#define N_LAYERS  3
#define NUM_GRAPHS 2048
#define BN_EPS    1e-5f

// ---------------------------------------------------------------------------
// Edge-parallel scatter-add: agg[dst[e]] += x[src[e]]   (64 ch per edge)
// thread i -> edge = i/16, channel-group (float4) = i%16
// 16 consecutive threads cover one edge's 64 channels -> coalesced 256B reads
// ---------------------------------------------------------------------------
__global__ __launch_bounds__(256) void scatter_add_kernel(
    const float* __restrict__ x,
    const int*   __restrict__ src,
    const int*   __restrict__ dst,
    float*       __restrict__ agg)
{
    const long long total = (long long)N_EDGES * 16;
    long long stride = (long long)gridDim.x * blockDim.x;
    for (long long i = (long long)blockIdx.x * blockDim.x + threadIdx.x;
         i < total; i += stride) {
        int e  = (int)(i >> 4);
        int cg = (int)(i & 15);
        int s = src[e];
        int d = dst[e];
        const float4 v = *reinterpret_cast<const float4*>(x + (size_t)s * CH + cg * 4);
        float* o = agg + (size_t)d * CH + cg * 4;
        atomicAdd(o + 0, v.x);
        atomicAdd(o + 1, v.y);
        atomicAdd(o + 2, v.z);
        atomicAdd(o + 3, v.w);
    }
}

// ---------------------------------------------------------------------------
// Fused GIN MLP: xout = relu( relu(BN((x+agg) @ W1 + b1)) @ W2 + b2 )
// One wave (64 lanes) per node; lane j owns output channel j.
// W1, W2 staged in LDS; input row broadcast via __shfl.
// ---------------------------------------------------------------------------
__global__ __launch_bounds__(256) void gin_mlp_kernel(
    const float* __restrict__ xin,  const float* __restrict__ agg,
    const float* __restrict__ W1,   const float* __restrict__ b1,
    const float* __restrict__ gamma,const float* __restrict__ beta,
    const float* __restrict__ mean, const float* __restrict__ var,
    const float* __restrict__ W2,   const float* __restrict__ b2,
    float* __restrict__ xout)
{
    __shared__ float w1[CH * CH];
    __shared__ float w2[CH * CH];
    __shared__ float scale_s[CH], shift_s[CH], b1_s[CH], b2_s[CH];

    for (int i = threadIdx.x; i < CH * CH; i += blockDim.x) {
        w1[i] = W1[i];
        w2[i] = W2[i];
    }
    if (threadIdx.x < CH) {
        int j = threadIdx.x;
        float sc = gamma[j] * rsqrtf(var[j] + BN_EPS);
        scale_s[j] = sc;
        shift_s[j] = beta[j] - mean[j] * sc;
        b1_s[j] = b1[j];
        b2_s[j] = b2[j];
    }
    __syncthreads();

    const int lane   = threadIdx.x & 63;
    const int wave   = threadIdx.x >> 6;
    const int gwave  = blockIdx.x * (blockDim.x >> 6) + wave;
    const int nwaves = gridDim.x * (blockDim.x >> 6);

    for (int node = gwave; node < N_NODES; node += nwaves) {
        const size_t base = (size_t)node * CH;
        float in_v = xin[base + lane] + agg[base + lane];

        float acc = b1_s[lane];
        #pragma unroll
        for (int k = 0; k < CH; ++k) {
            float v = __shfl(in_v, k, 64);
            acc = fmaf(v, w1[k * CH + lane], acc);
        }
        float t = fmaxf(fmaf(acc, scale_s[lane], shift_s[lane]), 0.0f);

        float acc2 = b2_s[lane];
        #pragma unroll
        for (int k = 0; k < CH; ++k) {
            float v = __shfl(t, k, 64);
            acc2 = fmaf(v, w2[k * CH + lane], acc2);
        }
        xout[base + lane] = fmaxf(acc2, 0.0f);
    }
}

// ---------------------------------------------------------------------------
// Global mean pool (sums + counts via atomics). One wave per node.
// ---------------------------------------------------------------------------
__global__ __launch_bounds__(256) void pool_kernel(
    const float* __restrict__ x, const int* __restrict__ batch,
    float* __restrict__ sums, float* __restrict__ counts)
{
    const int lane   = threadIdx.x & 63;
    const int gwave  = blockIdx.x * (blockDim.x >> 6) + (threadIdx.x >> 6);
    const int nwaves = gridDim.x * (blockDim.x >> 6);
    for (int node = gwave; node < N_NODES; node += nwaves) {
        int g = batch[node];
        atomicAdd(&sums[(size_t)g * CH + lane], x[(size_t)node * CH + lane]);
        if (lane == 0) atomicAdd(&counts[g], 1.0f);
    }
}

// ---------------------------------------------------------------------------
// Head: pooled = sums/counts; h = relu(pooled@mlpW1+b1); logits = h@mlpW2+b2;
// softmax over 2 classes. One wave per graph.
// ---------------------------------------------------------------------------
__global__ __launch_bounds__(256) void head_kernel(
    const float* __restrict__ sums, const float* __restrict__ counts,
    const float* __restrict__ W1, const float* __restrict__ b1,
    const float* __restrict__ W2, const float* __restrict__ b2,
    float* __restrict__ out)
{
    __shared__ float w1[CH * CH];
    __shared__ float b1s[CH];
    __shared__ float w2s[CH * 2];

    for (int i = threadIdx.x; i < CH * CH; i += blockDim.x) w1[i] = W1[i];
    if (threadIdx.x < CH)     b1s[threadIdx.x] = b1[threadIdx.x];
    if (threadIdx.x < CH * 2) w2s[threadIdx.x] = W2[threadIdx.x];
    __syncthreads();

    const int lane = threadIdx.x & 63;
    const int g = blockIdx.x * (blockDim.x >> 6) + (threadIdx.x >> 6);
    if (g >= NUM_GRAPHS) return;

    float cnt = fmaxf(counts[g], 1.0f);
    float p = sums[(size_t)g * CH + lane] / cnt;

    float acc = b1s[lane];
    #pragma unroll
    for (int k = 0; k < CH; ++k)
        acc = fmaf(__shfl(p, k, 64), w1[k * CH + lane], acc);
    float h = fmaxf(acc, 0.0f);

    float l0 = h * w2s[lane * 2 + 0];
    float l1 = h * w2s[lane * 2 + 1];
    #pragma unroll
    for (int off = 32; off > 0; off >>= 1) {
        l0 += __shfl_xor(l0, off, 64);
        l1 += __shfl_xor(l1, off, 64);
    }
    if (lane == 0) {
        l0 += b2[0];
        l1 += b2[1];
        float m  = fmaxf(l0, l1);
        float e0 = expf(l0 - m), e1 = expf(l1 - m);
        float s  = e0 + e1;
        out[(size_t)g * 2 + 0] = e0 / s;
        out[(size_t)g * 2 + 1] = e1 / s;
    }
}

extern "C" void kernel_launch(void* const* d_in, const int* in_sizes, int n_in,
                              void* d_out, int out_size, void* d_ws, size_t ws_size,
                              hipStream_t stream)
{
    const float* x      = (const float*)d_in[0];
    const int*   ei     = (const int*)  d_in[1];
    const int*   src    = ei;
    const int*   dst    = ei + N_EDGES;
    const int*   batch  = (const int*)  d_in[2];
    const float* convW1 = (const float*)d_in[3];
    const float* convb1 = (const float*)d_in[4];
    const float* gamma  = (const float*)d_in[5];
    const float* beta   = (const float*)d_in[6];
    const float* mean   = (const float*)d_in[7];
    const float* var    = (const float*)d_in[8];
    const float* convW2 = (const float*)d_in[9];
    const float* convb2 = (const float*)d_in[10];
    const float* mlpW1  = (const float*)d_in[11];
    const float* mlpb1  = (const float*)d_in[12];
    const float* mlpW2  = (const float*)d_in[13];
    const float* mlpb2  = (const float*)d_in[14];
    float* out = (float*)d_out;

    const size_t featElems = (size_t)N_NODES * CH;
    float* agg    = (float*)d_ws;
    float* xA     = agg + featElems;
    float* xB     = xA + featElems;
    float* sums   = xB + featElems;
    float* counts = sums + (size_t)NUM_GRAPHS * CH;   // contiguous after sums

    // zero pool accumulators once (ws is poisoned 0xAA before every launch)
    hipMemsetAsync(sums, 0, ((size_t)NUM_GRAPHS * CH + NUM_GRAPHS) * sizeof(float), stream);

    const float* cur = x;
    float* nxt = xA;
    for (int l = 0; l < N_LAYERS; ++l) {
        hipMemsetAsync(agg, 0, featElems * sizeof(float), stream);
        scatter_add_kernel<<<4096, 256, 0, stream>>>(cur, src, dst, agg);
        gin_mlp_kernel<<<1024, 256, 0, stream>>>(
            cur, agg,
            convW1 + (size_t)l * CH * CH, convb1 + (size_t)l * CH,
            gamma  + (size_t)l * CH, beta + (size_t)l * CH,
            mean   + (size_t)l * CH, var  + (size_t)l * CH,
            convW2 + (size_t)l * CH * CH, convb2 + (size_t)l * CH,
            nxt);
        cur = nxt;
        nxt = (nxt == xA) ? xB : xA;
    }

    pool_kernel<<<512, 256, 0, stream>>>(cur, batch, sums, counts);
    head_kernel<<<NUM_GRAPHS / 4, 256, 0, stream>>>(
        sums, counts, mlpW1, mlpb1, mlpW2, mlpb2, out);
}

// Round 5
// 1091.690 us; speedup vs baseline: 4.3091x; 4.3091x over previous
//
#include <hip/hip_runtime.h>

#define N_NODES   100000
#define N_EDGES   1600000
#define CH        64
#define N_LAYERS  3
#define NUM_GRAPHS 2048
#define BN_EPS    1e-5f

#define NP        100096          // N_NODES padded to 391*256
#define NBLK1     391             // ceil(100000/256)

// ---------------------------------------------------------------------------
// CSR build: deg histogram -> exclusive scan -> edge scatter (src ids by dst)
// ---------------------------------------------------------------------------
__global__ __launch_bounds__(256) void hist_kernel(
    const int* __restrict__ dst, int* __restrict__ deg)
{
    int e = blockIdx.x * 256 + threadIdx.x;
    if (e < N_EDGES) atomicAdd(&deg[dst[e]], 1);
}

__global__ __launch_bounds__(256) void scan1_kernel(
    const int* __restrict__ deg, int* __restrict__ rowptr, int* __restrict__ blockSums)
{
    __shared__ int tmp[256];
    int t = threadIdx.x;
    int i = blockIdx.x * 256 + t;
    int v = (i < N_NODES) ? deg[i] : 0;
    tmp[t] = v;
    __syncthreads();
    for (int off = 1; off < 256; off <<= 1) {
        int a = (t >= off) ? tmp[t - off] : 0;
        __syncthreads();
        tmp[t] += a;
        __syncthreads();
    }
    if (i < N_NODES) rowptr[i] = tmp[t] - v;      // exclusive
    if (t == 255) blockSums[blockIdx.x] = tmp[255];
}

__global__ __launch_bounds__(512) void scan2_kernel(
    const int* __restrict__ blockSums, int* __restrict__ blockPrefix)
{
    __shared__ int tmp[512];
    int t = threadIdx.x;
    int v = (t < NBLK1) ? blockSums[t] : 0;
    tmp[t] = v;
    __syncthreads();
    for (int off = 1; off < 512; off <<= 1) {
        int a = (t >= off) ? tmp[t - off] : 0;
        __syncthreads();
        tmp[t] += a;
        __syncthreads();
    }
    if (t < NBLK1) blockPrefix[t] = tmp[t] - v;   // exclusive
}

__global__ __launch_bounds__(256) void scan3_kernel(
    int* __restrict__ rowptr, int* __restrict__ cursor, const int* __restrict__ blockPrefix)
{
    int i = blockIdx.x * 256 + threadIdx.x;
    if (i < N_NODES) {
        int r = rowptr[i] + blockPrefix[blockIdx.x];
        rowptr[i] = r;
        cursor[i] = r;
    }
}

__global__ __launch_bounds__(256) void scatter_edges_kernel(
    const int* __restrict__ src, const int* __restrict__ dst,
    int* __restrict__ cursor, int* __restrict__ eidx)
{
    int e = blockIdx.x * 256 + threadIdx.x;
    if (e < N_EDGES) {
        int pos = atomicAdd(&cursor[dst[e]], 1);
        eidx[pos] = src[e];
    }
}

// ---------------------------------------------------------------------------
// Fused GIN layer (pull-mode): h = x[i] + sum_{j->i} x[j] via CSR gather,
// then xout = relu( relu(BN(h @ W1 + b1)) @ W2 + b2 ).
// One wave per node; lane j owns channel j. Weights staged in LDS.
// ---------------------------------------------------------------------------
__global__ __launch_bounds__(256) void gin_fused_kernel(
    const float* __restrict__ xin,
    const int*   __restrict__ rowptr, const int* __restrict__ deg,
    const int*   __restrict__ eidx,
    const float* __restrict__ W1,   const float* __restrict__ b1,
    const float* __restrict__ gamma,const float* __restrict__ beta,
    const float* __restrict__ mean, const float* __restrict__ var,
    const float* __restrict__ W2,   const float* __restrict__ b2,
    float* __restrict__ xout)
{
    __shared__ float w1[CH * CH];
    __shared__ float w2[CH * CH];
    __shared__ float scale_s[CH], shift_s[CH], b1_s[CH], b2_s[CH];

    for (int i = threadIdx.x; i < CH * CH; i += blockDim.x) {
        w1[i] = W1[i];
        w2[i] = W2[i];
    }
    if (threadIdx.x < CH) {
        int j = threadIdx.x;
        float sc = gamma[j] * rsqrtf(var[j] + BN_EPS);
        scale_s[j] = sc;
        shift_s[j] = beta[j] - mean[j] * sc;
        b1_s[j] = b1[j];
        b2_s[j] = b2[j];
    }
    __syncthreads();

    const int lane   = threadIdx.x & 63;
    const int wave   = threadIdx.x >> 6;
    const int gwave  = blockIdx.x * (blockDim.x >> 6) + wave;
    const int nwaves = gridDim.x * (blockDim.x >> 6);

    for (int node = gwave; node < N_NODES; node += nwaves) {
        const size_t base = (size_t)node * CH;
        float h = xin[base + lane];

        int e   = rowptr[node];
        int end = e + deg[node];
        // 4x unroll: batch the index loads so the 4 row-gathers overlap
        for (; e + 4 <= end; e += 4) {
            int s0 = eidx[e + 0], s1 = eidx[e + 1], s2 = eidx[e + 2], s3 = eidx[e + 3];
            float a0 = xin[(size_t)s0 * CH + lane];
            float a1 = xin[(size_t)s1 * CH + lane];
            float a2 = xin[(size_t)s2 * CH + lane];
            float a3 = xin[(size_t)s3 * CH + lane];
            h += a0; h += a1; h += a2; h += a3;
        }
        for (; e < end; ++e) h += xin[(size_t)eidx[e] * CH + lane];

        float acc = b1_s[lane];
        #pragma unroll
        for (int k = 0; k < CH; ++k) {
            float v = __shfl(h, k, 64);
            acc = fmaf(v, w1[k * CH + lane], acc);
        }
        float t = fmaxf(fmaf(acc, scale_s[lane], shift_s[lane]), 0.0f);

        float acc2 = b2_s[lane];
        #pragma unroll
        for (int k = 0; k < CH; ++k) {
            float v = __shfl(t, k, 64);
            acc2 = fmaf(v, w2[k * CH + lane], acc2);
        }
        xout[base + lane] = fmaxf(acc2, 0.0f);
    }
}

// ---------------------------------------------------------------------------
// Mean pool: batch is SORTED, so wave-per-graph binary-searches its segment
// and sums directly — no atomics, no counts buffer.
// ---------------------------------------------------------------------------
__global__ __launch_bounds__(256) void pool_mean_kernel(
    const float* __restrict__ x, const int* __restrict__ batch,
    float* __restrict__ pooled)
{
    const int lane = threadIdx.x & 63;
    const int g = blockIdx.x * (blockDim.x >> 6) + (threadIdx.x >> 6);
    if (g >= NUM_GRAPHS) return;

    // lower_bound(batch, g) and lower_bound(batch, g+1)
    int lo = 0, hi = N_NODES;
    while (lo < hi) { int mid = (lo + hi) >> 1; if (batch[mid] < g) lo = mid + 1; else hi = mid; }
    int start = lo;
    lo = start; hi = N_NODES;
    while (lo < hi) { int mid = (lo + hi) >> 1; if (batch[mid] < g + 1) lo = mid + 1; else hi = mid; }
    int end = lo;

    float s = 0.0f;
    for (int n = start; n < end; ++n) s += x[(size_t)n * CH + lane];
    int c = end - start;
    pooled[(size_t)g * CH + lane] = s / (float)(c > 0 ? c : 1);
}

// ---------------------------------------------------------------------------
// Head: h = relu(pooled@W1+b1); logits = h@W2+b2; softmax(2). Wave per graph.
// ---------------------------------------------------------------------------
__global__ __launch_bounds__(256) void head_kernel(
    const float* __restrict__ pooled,
    const float* __restrict__ W1, const float* __restrict__ b1,
    const float* __restrict__ W2, const float* __restrict__ b2,
    float* __restrict__ out)
{
    __shared__ float w1[CH * CH];
    __shared__ float b1s[CH];
    __shared__ float w2s[CH * 2];

    for (int i = threadIdx.x; i < CH * CH; i += blockDim.x) w1[i] = W1[i];
    if (threadIdx.x < CH)     b1s[threadIdx.x] = b1[threadIdx.x];
    if (threadIdx.x < CH * 2) w2s[threadIdx.x] = W2[threadIdx.x];
    __syncthreads();

    const int lane = threadIdx.x & 63;
    const int g = blockIdx.x * (blockDim.x >> 6) + (threadIdx.x >> 6);
    if (g >= NUM_GRAPHS) return;

    float p = pooled[(size_t)g * CH + lane];

    float acc = b1s[lane];
    #pragma unroll
    for (int k = 0; k < CH; ++k)
        acc = fmaf(__shfl(p, k, 64), w1[k * CH + lane], acc);
    float h = fmaxf(acc, 0.0f);

    float l0 = h * w2s[lane * 2 + 0];
    float l1 = h * w2s[lane * 2 + 1];
    #pragma unroll
    for (int off = 32; off > 0; off >>= 1) {
        l0 += __shfl_xor(l0, off, 64);
        l1 += __shfl_xor(l1, off, 64);
    }
    if (lane == 0) {
        l0 += b2[0];
        l1 += b2[1];
        float m  = fmaxf(l0, l1);
        float e0 = expf(l0 - m), e1 = expf(l1 - m);
        float s  = e0 + e1;
        out[(size_t)g * 2 + 0] = e0 / s;
        out[(size_t)g * 2 + 1] = e1 / s;
    }
}

extern "C" void kernel_launch(void* const* d_in, const int* in_sizes, int n_in,
                              void* d_out, int out_size, void* d_ws, size_t ws_size,
                              hipStream_t stream)
{
    const float* x      = (const float*)d_in[0];
    const int*   ei     = (const int*)  d_in[1];
    const int*   src    = ei;
    const int*   dst    = ei + N_EDGES;
    const int*   batch  = (const int*)  d_in[2];
    const float* convW1 = (const float*)d_in[3];
    const float* convb1 = (const float*)d_in[4];
    const float* gamma  = (const float*)d_in[5];
    const float* beta   = (const float*)d_in[6];
    const float* mean   = (const float*)d_in[7];
    const float* var    = (const float*)d_in[8];
    const float* convW2 = (const float*)d_in[9];
    const float* convb2 = (const float*)d_in[10];
    const float* mlpW1  = (const float*)d_in[11];
    const float* mlpb1  = (const float*)d_in[12];
    const float* mlpW2  = (const float*)d_in[13];
    const float* mlpb2  = (const float*)d_in[14];
    float* out = (float*)d_out;

    // ---- workspace layout (element offsets; int and float both 4 B) ----
    int* deg         = (int*)d_ws;                 // NP
    int* rowptr      = deg + NP;                   // NP
    int* cursor      = rowptr + NP;                // NP
    int* blockSums   = cursor + NP;                // 512
    int* blockPrefix = blockSums + 512;            // 512
    int* eidx        = blockPrefix + 512;          // N_EDGES
    float* xA        = (float*)(eidx + N_EDGES);   // N_NODES*CH
    float* xB        = xA + (size_t)N_NODES * CH;  // N_NODES*CH
    float* pooled    = xB + (size_t)N_NODES * CH;  // NUM_GRAPHS*CH

    // ---- CSR build (once per launch; ws is re-poisoned each call) ----
    hipMemsetAsync(deg, 0, NP * sizeof(int), stream);
    hist_kernel<<<(N_EDGES + 255) / 256, 256, 0, stream>>>(dst, deg);
    scan1_kernel<<<NBLK1, 256, 0, stream>>>(deg, rowptr, blockSums);
    scan2_kernel<<<1, 512, 0, stream>>>(blockSums, blockPrefix);
    scan3_kernel<<<NBLK1, 256, 0, stream>>>(rowptr, cursor, blockPrefix);
    scatter_edges_kernel<<<(N_EDGES + 255) / 256, 256, 0, stream>>>(src, dst, cursor, eidx);

    // ---- 3 fused GIN layers ----
    const float* cur = x;
    float* nxt = xA;
    for (int l = 0; l < N_LAYERS; ++l) {
        gin_fused_kernel<<<2048, 256, 0, stream>>>(
            cur, rowptr, deg, eidx,
            convW1 + (size_t)l * CH * CH, convb1 + (size_t)l * CH,
            gamma  + (size_t)l * CH, beta + (size_t)l * CH,
            mean   + (size_t)l * CH, var  + (size_t)l * CH,
            convW2 + (size_t)l * CH * CH, convb2 + (size_t)l * CH,
            nxt);
        cur = nxt;
        nxt = (nxt == xA) ? xB : xA;
    }

    // ---- pool + head ----
    pool_mean_kernel<<<NUM_GRAPHS / 4, 256, 0, stream>>>(cur, batch, pooled);
    head_kernel<<<NUM_GRAPHS / 4, 256, 0, stream>>>(
        pooled, mlpW1, mlpb1, mlpW2, mlpb2, out);
}

// Round 6
// 948.564 us; speedup vs baseline: 4.9592x; 1.1509x over previous
//
#include <hip/hip_runtime.h>

#define N_NODES   100000
#define N_EDGES   1600000
#define CH        64
#define N_LAYERS  3
#define NUM_GRAPHS 2048
#define BN_EPS    1e-5f

#define NP        100096          // N_NODES padded to 391*256
#define NBLK1     391             // ceil(100000/256)

// ---------------------------------------------------------------------------
// CSR build: deg histogram -> exclusive scan -> edge scatter (src ids by dst)
// ---------------------------------------------------------------------------
__global__ __launch_bounds__(256) void hist_kernel(
    const int* __restrict__ dst, int* __restrict__ deg)
{
    int e = blockIdx.x * 256 + threadIdx.x;
    if (e < N_EDGES) atomicAdd(&deg[dst[e]], 1);
}

__global__ __launch_bounds__(256) void scan1_kernel(
    const int* __restrict__ deg, int* __restrict__ rowptr, int* __restrict__ blockSums)
{
    __shared__ int tmp[256];
    int t = threadIdx.x;
    int i = blockIdx.x * 256 + t;
    int v = (i < N_NODES) ? deg[i] : 0;
    tmp[t] = v;
    __syncthreads();
    for (int off = 1; off < 256; off <<= 1) {
        int a = (t >= off) ? tmp[t - off] : 0;
        __syncthreads();
        tmp[t] += a;
        __syncthreads();
    }
    if (i < N_NODES) rowptr[i] = tmp[t] - v;      // exclusive
    if (t == 255) blockSums[blockIdx.x] = tmp[255];
}

__global__ __launch_bounds__(512) void scan2_kernel(
    const int* __restrict__ blockSums, int* __restrict__ blockPrefix)
{
    __shared__ int tmp[512];
    int t = threadIdx.x;
    int v = (t < NBLK1) ? blockSums[t] : 0;
    tmp[t] = v;
    __syncthreads();
    for (int off = 1; off < 512; off <<= 1) {
        int a = (t >= off) ? tmp[t - off] : 0;
        __syncthreads();
        tmp[t] += a;
        __syncthreads();
    }
    if (t < NBLK1) blockPrefix[t] = tmp[t] - v;   // exclusive
}

__global__ __launch_bounds__(256) void scan3_kernel(
    int* __restrict__ rowptr, int* __restrict__ cursor, const int* __restrict__ blockPrefix)
{
    int i = blockIdx.x * 256 + threadIdx.x;
    if (i < N_NODES) {
        int r = rowptr[i] + blockPrefix[blockIdx.x];
        rowptr[i] = r;
        cursor[i] = r;
    }
}

__global__ __launch_bounds__(256) void scatter_edges_kernel(
    const int* __restrict__ src, const int* __restrict__ dst,
    int* __restrict__ cursor, int* __restrict__ eidx)
{
    int e = blockIdx.x * 256 + threadIdx.x;
    if (e < N_EDGES) {
        int pos = atomicAdd(&cursor[dst[e]], 1);
        eidx[pos] = src[e];
    }
}

// ---------------------------------------------------------------------------
// Aggregate (pull): h[n] = x[n] + sum_{j->n} x[j].
// Thread = (node, float4 channel group): 1.6M threads, max TLP, 16 B/lane.
// Wave covers 4 nodes -> 16 independent row-gathers in flight w/ 4x unroll.
// ---------------------------------------------------------------------------
__global__ __launch_bounds__(256) void aggregate_kernel(
    const float* __restrict__ xin,
    const int*   __restrict__ rowptr, const int* __restrict__ deg,
    const int*   __restrict__ eidx,
    float*       __restrict__ h)
{
    int tid = blockIdx.x * 256 + threadIdx.x;
    if (tid >= N_NODES * 16) return;
    int n  = tid >> 4;
    int cg = tid & 15;

    const float4* xv = (const float4*)xin;
    float4 acc = xv[(size_t)n * 16 + cg];

    int e   = rowptr[n];
    int end = e + deg[n];
    for (; e + 4 <= end; e += 4) {
        int s0 = eidx[e + 0], s1 = eidx[e + 1], s2 = eidx[e + 2], s3 = eidx[e + 3];
        float4 a = xv[(size_t)s0 * 16 + cg];
        float4 b = xv[(size_t)s1 * 16 + cg];
        float4 c = xv[(size_t)s2 * 16 + cg];
        float4 d = xv[(size_t)s3 * 16 + cg];
        acc.x += a.x; acc.y += a.y; acc.z += a.z; acc.w += a.w;
        acc.x += b.x; acc.y += b.y; acc.z += b.z; acc.w += b.w;
        acc.x += c.x; acc.y += c.y; acc.z += c.z; acc.w += c.w;
        acc.x += d.x; acc.y += d.y; acc.z += d.z; acc.w += d.w;
    }
    for (; e < end; ++e) {
        float4 a = xv[(size_t)eidx[e] * 16 + cg];
        acc.x += a.x; acc.y += a.y; acc.z += a.z; acc.w += a.w;
    }
    ((float4*)h)[(size_t)n * 16 + cg] = acc;
}

// ---------------------------------------------------------------------------
// MLP: xout = relu( relu(BN(h @ W1 + b1)) @ W2 + b2 ).  In-place safe
// (each wave reads its node's row fully before writing it back).
// One wave per node; lane j owns channel j. Weights staged in LDS.
// ---------------------------------------------------------------------------
__global__ __launch_bounds__(256) void mlp_kernel(
    const float* __restrict__ hin,
    const float* __restrict__ W1,   const float* __restrict__ b1,
    const float* __restrict__ gamma,const float* __restrict__ beta,
    const float* __restrict__ mean, const float* __restrict__ var,
    const float* __restrict__ W2,   const float* __restrict__ b2,
    float* __restrict__ xout)
{
    __shared__ float w1[CH * CH];
    __shared__ float w2[CH * CH];
    __shared__ float scale_s[CH], shift_s[CH], b1_s[CH], b2_s[CH];

    for (int i = threadIdx.x; i < CH * CH; i += blockDim.x) {
        w1[i] = W1[i];
        w2[i] = W2[i];
    }
    if (threadIdx.x < CH) {
        int j = threadIdx.x;
        float sc = gamma[j] * rsqrtf(var[j] + BN_EPS);
        scale_s[j] = sc;
        shift_s[j] = beta[j] - mean[j] * sc;
        b1_s[j] = b1[j];
        b2_s[j] = b2[j];
    }
    __syncthreads();

    const int lane   = threadIdx.x & 63;
    const int wave   = threadIdx.x >> 6;
    const int gwave  = blockIdx.x * (blockDim.x >> 6) + wave;
    const int nwaves = gridDim.x * (blockDim.x >> 6);

    for (int node = gwave; node < N_NODES; node += nwaves) {
        const size_t base = (size_t)node * CH;
        float h = hin[base + lane];

        float acc = b1_s[lane];
        #pragma unroll
        for (int k = 0; k < CH; ++k) {
            float v = __shfl(h, k, 64);
            acc = fmaf(v, w1[k * CH + lane], acc);
        }
        float t = fmaxf(fmaf(acc, scale_s[lane], shift_s[lane]), 0.0f);

        float acc2 = b2_s[lane];
        #pragma unroll
        for (int k = 0; k < CH; ++k) {
            float v = __shfl(t, k, 64);
            acc2 = fmaf(v, w2[k * CH + lane], acc2);
        }
        xout[base + lane] = fmaxf(acc2, 0.0f);
    }
}

// ---------------------------------------------------------------------------
// Mean pool: batch is SORTED -> wave-per-graph binary search + direct sum.
// ---------------------------------------------------------------------------
__global__ __launch_bounds__(256) void pool_mean_kernel(
    const float* __restrict__ x, const int* __restrict__ batch,
    float* __restrict__ pooled)
{
    const int lane = threadIdx.x & 63;
    const int g = blockIdx.x * (blockDim.x >> 6) + (threadIdx.x >> 6);
    if (g >= NUM_GRAPHS) return;

    int lo = 0, hi = N_NODES;
    while (lo < hi) { int mid = (lo + hi) >> 1; if (batch[mid] < g) lo = mid + 1; else hi = mid; }
    int start = lo;
    lo = start; hi = N_NODES;
    while (lo < hi) { int mid = (lo + hi) >> 1; if (batch[mid] < g + 1) lo = mid + 1; else hi = mid; }
    int end = lo;

    float s = 0.0f;
    for (int n = start; n < end; ++n) s += x[(size_t)n * CH + lane];
    int c = end - start;
    pooled[(size_t)g * CH + lane] = s / (float)(c > 0 ? c : 1);
}

// ---------------------------------------------------------------------------
// Head: h = relu(pooled@W1+b1); logits = h@W2+b2; softmax(2). Wave per graph.
// ---------------------------------------------------------------------------
__global__ __launch_bounds__(256) void head_kernel(
    const float* __restrict__ pooled,
    const float* __restrict__ W1, const float* __restrict__ b1,
    const float* __restrict__ W2, const float* __restrict__ b2,
    float* __restrict__ out)
{
    __shared__ float w1[CH * CH];
    __shared__ float b1s[CH];
    __shared__ float w2s[CH * 2];

    for (int i = threadIdx.x; i < CH * CH; i += blockDim.x) w1[i] = W1[i];
    if (threadIdx.x < CH)     b1s[threadIdx.x] = b1[threadIdx.x];
    if (threadIdx.x < CH * 2) w2s[threadIdx.x] = W2[threadIdx.x];
    __syncthreads();

    const int lane = threadIdx.x & 63;
    const int g = blockIdx.x * (blockDim.x >> 6) + (threadIdx.x >> 6);
    if (g >= NUM_GRAPHS) return;

    float p = pooled[(size_t)g * CH + lane];

    float acc = b1s[lane];
    #pragma unroll
    for (int k = 0; k < CH; ++k)
        acc = fmaf(__shfl(p, k, 64), w1[k * CH + lane], acc);
    float h = fmaxf(acc, 0.0f);

    float l0 = h * w2s[lane * 2 + 0];
    float l1 = h * w2s[lane * 2 + 1];
    #pragma unroll
    for (int off = 32; off > 0; off >>= 1) {
        l0 += __shfl_xor(l0, off, 64);
        l1 += __shfl_xor(l1, off, 64);
    }
    if (lane == 0) {
        l0 += b2[0];
        l1 += b2[1];
        float m  = fmaxf(l0, l1);
        float e0 = expf(l0 - m), e1 = expf(l1 - m);
        float s  = e0 + e1;
        out[(size_t)g * 2 + 0] = e0 / s;
        out[(size_t)g * 2 + 1] = e1 / s;
    }
}

extern "C" void kernel_launch(void* const* d_in, const int* in_sizes, int n_in,
                              void* d_out, int out_size, void* d_ws, size_t ws_size,
                              hipStream_t stream)
{
    const float* x      = (const float*)d_in[0];
    const int*   ei     = (const int*)  d_in[1];
    const int*   src    = ei;
    const int*   dst    = ei + N_EDGES;
    const int*   batch  = (const int*)  d_in[2];
    const float* convW1 = (const float*)d_in[3];
    const float* convb1 = (const float*)d_in[4];
    const float* gamma  = (const float*)d_in[5];
    const float* beta   = (const float*)d_in[6];
    const float* mean   = (const float*)d_in[7];
    const float* var    = (const float*)d_in[8];
    const float* convW2 = (const float*)d_in[9];
    const float* convb2 = (const float*)d_in[10];
    const float* mlpW1  = (const float*)d_in[11];
    const float* mlpb1  = (const float*)d_in[12];
    const float* mlpW2  = (const float*)d_in[13];
    const float* mlpb2  = (const float*)d_in[14];
    float* out = (float*)d_out;

    // ---- workspace layout (element offsets; int and float both 4 B) ----
    int* deg         = (int*)d_ws;                 // NP
    int* rowptr      = deg + NP;                   // NP
    int* cursor      = rowptr + NP;                // NP
    int* blockSums   = cursor + NP;                // 512
    int* blockPrefix = blockSums + 512;            // 512
    int* eidx        = blockPrefix + 512;          // N_EDGES
    float* xA        = (float*)(eidx + N_EDGES);   // N_NODES*CH
    float* xB        = xA + (size_t)N_NODES * CH;  // N_NODES*CH
    float* pooled    = xB + (size_t)N_NODES * CH;  // NUM_GRAPHS*CH

    // ---- CSR build (once per launch; ws is re-poisoned each call) ----
    hipMemsetAsync(deg, 0, NP * sizeof(int), stream);
    hist_kernel<<<(N_EDGES + 255) / 256, 256, 0, stream>>>(dst, deg);
    scan1_kernel<<<NBLK1, 256, 0, stream>>>(deg, rowptr, blockSums);
    scan2_kernel<<<1, 512, 0, stream>>>(blockSums, blockPrefix);
    scan3_kernel<<<NBLK1, 256, 0, stream>>>(rowptr, cursor, blockPrefix);
    scatter_edges_kernel<<<(N_EDGES + 255) / 256, 256, 0, stream>>>(src, dst, cursor, eidx);

    const int aggGrid = (N_NODES * 16 + 255) / 256;   // 6250 blocks

    // ---- 3 GIN layers: aggregate (TLP gather) then MLP (in-place) ----
    // L0: agg(x -> A);  mlp(A)
    aggregate_kernel<<<aggGrid, 256, 0, stream>>>(x, rowptr, deg, eidx, xA);
    mlp_kernel<<<2048, 256, 0, stream>>>(xA,
        convW1, convb1, gamma, beta, mean, var, convW2, convb2, xA);
    // L1: agg(A -> B);  mlp(B)
    aggregate_kernel<<<aggGrid, 256, 0, stream>>>(xA, rowptr, deg, eidx, xB);
    mlp_kernel<<<2048, 256, 0, stream>>>(xB,
        convW1 + CH*CH, convb1 + CH, gamma + CH, beta + CH, mean + CH, var + CH,
        convW2 + CH*CH, convb2 + CH, xB);
    // L2: agg(B -> A);  mlp(A)
    aggregate_kernel<<<aggGrid, 256, 0, stream>>>(xB, rowptr, deg, eidx, xA);
    mlp_kernel<<<2048, 256, 0, stream>>>(xA,
        convW1 + 2*CH*CH, convb1 + 2*CH, gamma + 2*CH, beta + 2*CH, mean + 2*CH,
        var + 2*CH, convW2 + 2*CH*CH, convb2 + 2*CH, xA);

    // ---- pool + head ----
    pool_mean_kernel<<<NUM_GRAPHS / 4, 256, 0, stream>>>(xA, batch, pooled);
    head_kernel<<<NUM_GRAPHS / 4, 256, 0, stream>>>(
        pooled, mlpW1, mlpb1, mlpW2, mlpb2, out);
}

// Round 7
// 661.520 us; speedup vs baseline: 7.1111x; 1.4339x over previous
//
#include <hip/hip_runtime.h>

#define N_NODES   100000
#define N_EDGES   1600000
#define CH        64
#define N_LAYERS  3
#define NUM_GRAPHS 2048
#define BN_EPS    1e-5f
#define NXCD      8

#define NP        100096          // N_NODES padded to 391*256
#define NBLK1     391             // ceil(100000/256)

// ---------------------------------------------------------------------------
// CSR build: deg histogram -> exclusive scan -> edge scatter (src ids by dst)
// ---------------------------------------------------------------------------
__global__ __launch_bounds__(256) void hist_kernel(
    const int* __restrict__ dst, int* __restrict__ deg)
{
    int e = blockIdx.x * 256 + threadIdx.x;
    if (e < N_EDGES) atomicAdd(&deg[dst[e]], 1);
}

__global__ __launch_bounds__(256) void scan1_kernel(
    const int* __restrict__ deg, int* __restrict__ rowptr, int* __restrict__ blockSums)
{
    __shared__ int tmp[256];
    int t = threadIdx.x;
    int i = blockIdx.x * 256 + t;
    int v = (i < N_NODES) ? deg[i] : 0;
    tmp[t] = v;
    __syncthreads();
    for (int off = 1; off < 256; off <<= 1) {
        int a = (t >= off) ? tmp[t - off] : 0;
        __syncthreads();
        tmp[t] += a;
        __syncthreads();
    }
    if (i < N_NODES) rowptr[i] = tmp[t] - v;      // exclusive
    if (t == 255) blockSums[blockIdx.x] = tmp[255];
}

__global__ __launch_bounds__(512) void scan2_kernel(
    const int* __restrict__ blockSums, int* __restrict__ blockPrefix)
{
    __shared__ int tmp[512];
    int t = threadIdx.x;
    int v = (t < NBLK1) ? blockSums[t] : 0;
    tmp[t] = v;
    __syncthreads();
    for (int off = 1; off < 512; off <<= 1) {
        int a = (t >= off) ? tmp[t - off] : 0;
        __syncthreads();
        tmp[t] += a;
        __syncthreads();
    }
    if (t < NBLK1) blockPrefix[t] = tmp[t] - v;   // exclusive
}

__global__ __launch_bounds__(256) void scan3_kernel(
    int* __restrict__ rowptr, int* __restrict__ cursor, const int* __restrict__ blockPrefix)
{
    int i = blockIdx.x * 256 + threadIdx.x;
    if (i < N_NODES) {
        int r = rowptr[i] + blockPrefix[blockIdx.x];
        rowptr[i] = r;
        cursor[i] = r;
    }
}

// XCD-partitioned edge scatter: block-group (blockIdx%8) owns dst slice
// [xcd*12500, ...). Each eidx/cursor cache line is then written by one XCD
// only -> no cross-XCD line bounce (WRITE_SIZE was 105 MB for 6.4 MB data).
// Correct for ANY block->XCD mapping: every edge is written exactly once.
__global__ __launch_bounds__(256) void scatter_edges_kernel(
    const int* __restrict__ src, const int* __restrict__ dst,
    int* __restrict__ cursor, int* __restrict__ eidx)
{
    const int xcd = blockIdx.x & (NXCD - 1);
    const int ib  = blockIdx.x >> 3;
    const int nbx = gridDim.x >> 3;
    const int lo  = xcd * (N_NODES / NXCD);
    const int hi  = (xcd == NXCD - 1) ? N_NODES : lo + (N_NODES / NXCD);
    for (int e = ib * 256 + threadIdx.x; e < N_EDGES; e += nbx * 256) {
        int d = dst[e];
        if (d >= lo && d < hi) {
            int pos = atomicAdd(&cursor[d], 1);
            eidx[pos] = src[e];
        }
    }
}

// ---------------------------------------------------------------------------
// Aggregate (pull): h[n] = x[n] + sum_{j->n} x[j].
// Thread = (node, float4 channel group): 1.6M threads, max TLP, 16 B/lane.
// ---------------------------------------------------------------------------
__global__ __launch_bounds__(256) void aggregate_kernel(
    const float* __restrict__ xin,
    const int*   __restrict__ rowptr, const int* __restrict__ deg,
    const int*   __restrict__ eidx,
    float*       __restrict__ h)
{
    int tid = blockIdx.x * 256 + threadIdx.x;
    if (tid >= N_NODES * 16) return;
    int n  = tid >> 4;
    int cg = tid & 15;

    const float4* xv = (const float4*)xin;
    float4 acc = xv[(size_t)n * 16 + cg];

    int e   = rowptr[n];
    int end = e + deg[n];
    for (; e + 4 <= end; e += 4) {
        int s0 = eidx[e + 0], s1 = eidx[e + 1], s2 = eidx[e + 2], s3 = eidx[e + 3];
        float4 a = xv[(size_t)s0 * 16 + cg];
        float4 b = xv[(size_t)s1 * 16 + cg];
        float4 c = xv[(size_t)s2 * 16 + cg];
        float4 d = xv[(size_t)s3 * 16 + cg];
        acc.x += a.x; acc.y += a.y; acc.z += a.z; acc.w += a.w;
        acc.x += b.x; acc.y += b.y; acc.z += b.z; acc.w += b.w;
        acc.x += c.x; acc.y += c.y; acc.z += c.z; acc.w += c.w;
        acc.x += d.x; acc.y += d.y; acc.z += d.z; acc.w += d.w;
    }
    for (; e < end; ++e) {
        float4 a = xv[(size_t)eidx[e] * 16 + cg];
        acc.x += a.x; acc.y += a.y; acc.z += a.z; acc.w += a.w;
    }
    ((float4*)h)[(size_t)n * 16 + cg] = acc;
}

// ---------------------------------------------------------------------------
// MLP, node-per-lane: lane owns one node's full row in VGPRs.
// Weight loads are lane-uniform -> compiler emits s_load into SGPRs ->
// v_fmac with SGPR operand: 1 VALU op per MAC, zero LDS, zero shfl.
// 64 independent FMA chains per lane => full latency hiding at any occupancy.
// In-place safe (lane reads only its own row, then writes it).
// ---------------------------------------------------------------------------
__global__ __launch_bounds__(256) void mlp_kernel(
    const float* __restrict__ hin,
    const float* __restrict__ W1,   const float* __restrict__ b1,
    const float* __restrict__ gamma,const float* __restrict__ beta,
    const float* __restrict__ mean, const float* __restrict__ var,
    const float* __restrict__ W2,   const float* __restrict__ b2,
    float* __restrict__ xout)
{
    const int lane = threadIdx.x & 63;
    const int wv   = threadIdx.x >> 6;
    const int gw   = blockIdx.x * 4 + wv;
    const int n    = gw * 64 + lane;
    const int nc   = (n < N_NODES) ? n : (N_NODES - 1);

    const float* hrow = hin + (size_t)nc * CH;
    float h[CH];
    #pragma unroll
    for (int q = 0; q < CH / 4; ++q) {
        float4 v = *(const float4*)(hrow + q * 4);
        h[q * 4 + 0] = v.x; h[q * 4 + 1] = v.y;
        h[q * 4 + 2] = v.z; h[q * 4 + 3] = v.w;
    }

    // GEMM1: a[j] = b1[j] + sum_k h[k] * W1[k][j]
    float a[CH];
    #pragma unroll
    for (int j = 0; j < CH; ++j) a[j] = b1[j];
    #pragma unroll
    for (int k = 0; k < CH; ++k) {
        float hk = h[k];
        #pragma unroll
        for (int j = 0; j < CH; ++j)
            a[j] = fmaf(hk, W1[k * CH + j], a[j]);
    }

    // BN (eval) + ReLU
    float t[CH];
    #pragma unroll
    for (int j = 0; j < CH; ++j) {
        float sc = gamma[j] * rsqrtf(var[j] + BN_EPS);
        float sh = beta[j] - mean[j] * sc;
        t[j] = fmaxf(fmaf(a[j], sc, sh), 0.0f);
    }

    // GEMM2: c[j] = b2[j] + sum_k t[k] * W2[k][j]
    float c[CH];
    #pragma unroll
    for (int j = 0; j < CH; ++j) c[j] = b2[j];
    #pragma unroll
    for (int k = 0; k < CH; ++k) {
        float tk = t[k];
        #pragma unroll
        for (int j = 0; j < CH; ++j)
            c[j] = fmaf(tk, W2[k * CH + j], c[j]);
    }

    if (n < N_NODES) {
        float* orow = xout + (size_t)n * CH;
        #pragma unroll
        for (int q = 0; q < CH / 4; ++q) {
            float4 v;
            v.x = fmaxf(c[q * 4 + 0], 0.0f);
            v.y = fmaxf(c[q * 4 + 1], 0.0f);
            v.z = fmaxf(c[q * 4 + 2], 0.0f);
            v.w = fmaxf(c[q * 4 + 3], 0.0f);
            *(float4*)(orow + q * 4) = v;
        }
    }
}

// ---------------------------------------------------------------------------
// Mean pool: batch is SORTED -> wave-per-graph binary search + direct sum.
// ---------------------------------------------------------------------------
__global__ __launch_bounds__(256) void pool_mean_kernel(
    const float* __restrict__ x, const int* __restrict__ batch,
    float* __restrict__ pooled)
{
    const int lane = threadIdx.x & 63;
    const int g = blockIdx.x * (blockDim.x >> 6) + (threadIdx.x >> 6);
    if (g >= NUM_GRAPHS) return;

    int lo = 0, hi = N_NODES;
    while (lo < hi) { int mid = (lo + hi) >> 1; if (batch[mid] < g) lo = mid + 1; else hi = mid; }
    int start = lo;
    lo = start; hi = N_NODES;
    while (lo < hi) { int mid = (lo + hi) >> 1; if (batch[mid] < g + 1) lo = mid + 1; else hi = mid; }
    int end = lo;

    float s = 0.0f;
    for (int n = start; n < end; ++n) s += x[(size_t)n * CH + lane];
    int c = end - start;
    pooled[(size_t)g * CH + lane] = s / (float)(c > 0 ? c : 1);
}

// ---------------------------------------------------------------------------
// Head: h = relu(pooled@W1+b1); logits = h@W2+b2; softmax(2). Wave per graph.
// ---------------------------------------------------------------------------
__global__ __launch_bounds__(256) void head_kernel(
    const float* __restrict__ pooled,
    const float* __restrict__ W1, const float* __restrict__ b1,
    const float* __restrict__ W2, const float* __restrict__ b2,
    float* __restrict__ out)
{
    __shared__ float w1[CH * CH];
    __shared__ float b1s[CH];
    __shared__ float w2s[CH * 2];

    for (int i = threadIdx.x; i < CH * CH; i += blockDim.x) w1[i] = W1[i];
    if (threadIdx.x < CH)     b1s[threadIdx.x] = b1[threadIdx.x];
    if (threadIdx.x < CH * 2) w2s[threadIdx.x] = W2[threadIdx.x];
    __syncthreads();

    const int lane = threadIdx.x & 63;
    const int g = blockIdx.x * (blockDim.x >> 6) + (threadIdx.x >> 6);
    if (g >= NUM_GRAPHS) return;

    float p = pooled[(size_t)g * CH + lane];

    float acc = b1s[lane];
    #pragma unroll
    for (int k = 0; k < CH; ++k)
        acc = fmaf(__shfl(p, k, 64), w1[k * CH + lane], acc);
    float h = fmaxf(acc, 0.0f);

    float l0 = h * w2s[lane * 2 + 0];
    float l1 = h * w2s[lane * 2 + 1];
    #pragma unroll
    for (int off = 32; off > 0; off >>= 1) {
        l0 += __shfl_xor(l0, off, 64);
        l1 += __shfl_xor(l1, off, 64);
    }
    if (lane == 0) {
        l0 += b2[0];
        l1 += b2[1];
        float m  = fmaxf(l0, l1);
        float e0 = expf(l0 - m), e1 = expf(l1 - m);
        float s  = e0 + e1;
        out[(size_t)g * 2 + 0] = e0 / s;
        out[(size_t)g * 2 + 1] = e1 / s;
    }
}

extern "C" void kernel_launch(void* const* d_in, const int* in_sizes, int n_in,
                              void* d_out, int out_size, void* d_ws, size_t ws_size,
                              hipStream_t stream)
{
    const float* x      = (const float*)d_in[0];
    const int*   ei     = (const int*)  d_in[1];
    const int*   src    = ei;
    const int*   dst    = ei + N_EDGES;
    const int*   batch  = (const int*)  d_in[2];
    const float* convW1 = (const float*)d_in[3];
    const float* convb1 = (const float*)d_in[4];
    const float* gamma  = (const float*)d_in[5];
    const float* beta   = (const float*)d_in[6];
    const float* mean   = (const float*)d_in[7];
    const float* var    = (const float*)d_in[8];
    const float* convW2 = (const float*)d_in[9];
    const float* convb2 = (const float*)d_in[10];
    const float* mlpW1  = (const float*)d_in[11];
    const float* mlpb1  = (const float*)d_in[12];
    const float* mlpW2  = (const float*)d_in[13];
    const float* mlpb2  = (const float*)d_in[14];
    float* out = (float*)d_out;

    // ---- workspace layout (element offsets; int and float both 4 B) ----
    int* deg         = (int*)d_ws;                 // NP
    int* rowptr      = deg + NP;                   // NP
    int* cursor      = rowptr + NP;                // NP
    int* blockSums   = cursor + NP;                // 512
    int* blockPrefix = blockSums + 512;            // 512
    int* eidx        = blockPrefix + 512;          // N_EDGES
    float* xA        = (float*)(eidx + N_EDGES);   // N_NODES*CH
    float* xB        = xA + (size_t)N_NODES * CH;  // N_NODES*CH
    float* pooled    = xB + (size_t)N_NODES * CH;  // NUM_GRAPHS*CH

    // ---- CSR build (once per launch; ws is re-poisoned each call) ----
    hipMemsetAsync(deg, 0, NP * sizeof(int), stream);
    hist_kernel<<<(N_EDGES + 255) / 256, 256, 0, stream>>>(dst, deg);
    scan1_kernel<<<NBLK1, 256, 0, stream>>>(deg, rowptr, blockSums);
    scan2_kernel<<<1, 512, 0, stream>>>(blockSums, blockPrefix);
    scan3_kernel<<<NBLK1, 256, 0, stream>>>(rowptr, cursor, blockPrefix);
    scatter_edges_kernel<<<2048, 256, 0, stream>>>(src, dst, cursor, eidx);

    const int aggGrid = (N_NODES * 16 + 255) / 256;   // 6250 blocks
    const int mlpGrid = NBLK1;                        // 391 blocks: wave=64 nodes

    // ---- 3 GIN layers: aggregate (TLP gather) then MLP (in-place) ----
    aggregate_kernel<<<aggGrid, 256, 0, stream>>>(x, rowptr, deg, eidx, xA);
    mlp_kernel<<<mlpGrid, 256, 0, stream>>>(xA,
        convW1, convb1, gamma, beta, mean, var, convW2, convb2, xA);
    aggregate_kernel<<<aggGrid, 256, 0, stream>>>(xA, rowptr, deg, eidx, xB);
    mlp_kernel<<<mlpGrid, 256, 0, stream>>>(xB,
        convW1 + CH*CH, convb1 + CH, gamma + CH, beta + CH, mean + CH, var + CH,
        convW2 + CH*CH, convb2 + CH, xB);
    aggregate_kernel<<<aggGrid, 256, 0, stream>>>(xB, rowptr, deg, eidx, xA);
    mlp_kernel<<<mlpGrid, 256, 0, stream>>>(xA,
        convW1 + 2*CH*CH, convb1 + 2*CH, gamma + 2*CH, beta + 2*CH, mean + 2*CH,
        var + 2*CH, convW2 + 2*CH*CH, convb2 + 2*CH, xA);

    // ---- pool + head ----
    pool_mean_kernel<<<NUM_GRAPHS / 4, 256, 0, stream>>>(xA, batch, pooled);
    head_kernel<<<NUM_GRAPHS / 4, 256, 0, stream>>>(
        pooled, mlpW1, mlpb1, mlpW2, mlpb2, out);
}

// Round 9
// 600.189 us; speedup vs baseline: 7.8378x; 1.1022x over previous
//
#include <hip/hip_runtime.h>

#define N_NODES   100000
#define N_EDGES   1600000
#define CH        64
#define N_LAYERS  3
#define NUM_GRAPHS 2048
#define BN_EPS    1e-5f
#define NXCD      8

#define NP        100096          // N_NODES padded to 391*256
#define NBLK1     391             // ceil(100000/256)
#define LDSTRIDE  65              // 64+1: (65*lane+k)%32 = (lane+k)%32, conflict-free

// ---------------------------------------------------------------------------
// CSR build: deg histogram -> exclusive scan -> edge scatter (src ids by dst)
// ---------------------------------------------------------------------------
__global__ __launch_bounds__(256) void hist_kernel(
    const int* __restrict__ dst, int* __restrict__ deg)
{
    int e = blockIdx.x * 256 + threadIdx.x;
    if (e < N_EDGES) atomicAdd(&deg[dst[e]], 1);
}

__global__ __launch_bounds__(256) void scan1_kernel(
    const int* __restrict__ deg, int* __restrict__ rowptr, int* __restrict__ blockSums)
{
    __shared__ int tmp[256];
    int t = threadIdx.x;
    int i = blockIdx.x * 256 + t;
    int v = (i < N_NODES) ? deg[i] : 0;
    tmp[t] = v;
    __syncthreads();
    for (int off = 1; off < 256; off <<= 1) {
        int a = (t >= off) ? tmp[t - off] : 0;
        __syncthreads();
        tmp[t] += a;
        __syncthreads();
    }
    if (i < N_NODES) rowptr[i] = tmp[t] - v;      // exclusive
    if (t == 255) blockSums[blockIdx.x] = tmp[255];
}

__global__ __launch_bounds__(512) void scan2_kernel(
    const int* __restrict__ blockSums, int* __restrict__ blockPrefix)
{
    __shared__ int tmp[512];
    int t = threadIdx.x;
    int v = (t < NBLK1) ? blockSums[t] : 0;
    tmp[t] = v;
    __syncthreads();
    for (int off = 1; off < 512; off <<= 1) {
        int a = (t >= off) ? tmp[t - off] : 0;
        __syncthreads();
        tmp[t] += a;
        __syncthreads();
    }
    if (t < NBLK1) blockPrefix[t] = tmp[t] - v;   // exclusive
}

__global__ __launch_bounds__(256) void scan3_kernel(
    int* __restrict__ rowptr, int* __restrict__ cursor, const int* __restrict__ blockPrefix)
{
    int i = blockIdx.x * 256 + threadIdx.x;
    if (i < N_NODES) {
        int r = rowptr[i] + blockPrefix[blockIdx.x];
        rowptr[i] = r;
        cursor[i] = r;
    }
}

// XCD-partitioned edge scatter (kills cross-XCD line bounce on cursor/eidx).
__global__ __launch_bounds__(256) void scatter_edges_kernel(
    const int* __restrict__ src, const int* __restrict__ dst,
    int* __restrict__ cursor, int* __restrict__ eidx)
{
    const int xcd = blockIdx.x & (NXCD - 1);
    const int ib  = blockIdx.x >> 3;
    const int nbx = gridDim.x >> 3;
    const int lo  = xcd * (N_NODES / NXCD);
    const int hi  = (xcd == NXCD - 1) ? N_NODES : lo + (N_NODES / NXCD);
    for (int e = ib * 256 + threadIdx.x; e < N_EDGES; e += nbx * 256) {
        int d = dst[e];
        if (d >= lo && d < hi) {
            int pos = atomicAdd(&cursor[d], 1);
            eidx[pos] = src[e];
        }
    }
}

// ---------------------------------------------------------------------------
// Aggregate (pull): h[n] = x[n] + sum_{j->n} x[j].
// Thread = (node, float4 channel group): 1.6M threads, max TLP, 16 B/lane.
// ---------------------------------------------------------------------------
__global__ __launch_bounds__(256) void aggregate_kernel(
    const float* __restrict__ xin,
    const int*   __restrict__ rowptr, const int* __restrict__ deg,
    const int*   __restrict__ eidx,
    float*       __restrict__ h)
{
    int tid = blockIdx.x * 256 + threadIdx.x;
    if (tid >= N_NODES * 16) return;
    int n  = tid >> 4;
    int cg = tid & 15;

    const float4* xv = (const float4*)xin;
    float4 acc = xv[(size_t)n * 16 + cg];

    int e   = rowptr[n];
    int end = e + deg[n];
    for (; e + 4 <= end; e += 4) {
        int s0 = eidx[e + 0], s1 = eidx[e + 1], s2 = eidx[e + 2], s3 = eidx[e + 3];
        float4 a = xv[(size_t)s0 * 16 + cg];
        float4 b = xv[(size_t)s1 * 16 + cg];
        float4 c = xv[(size_t)s2 * 16 + cg];
        float4 d = xv[(size_t)s3 * 16 + cg];
        acc.x += a.x; acc.y += a.y; acc.z += a.z; acc.w += a.w;
        acc.x += b.x; acc.y += b.y; acc.z += b.z; acc.w += b.w;
        acc.x += c.x; acc.y += c.y; acc.z += c.z; acc.w += c.w;
        acc.x += d.x; acc.y += d.y; acc.z += d.z; acc.w += d.w;
    }
    for (; e < end; ++e) {
        float4 a = xv[(size_t)eidx[e] * 16 + cg];
        acc.x += a.x; acc.y += a.y; acc.z += a.z; acc.w += a.w;
    }
    ((float4*)h)[(size_t)n * 16 + cg] = acc;
}

// ---------------------------------------------------------------------------
// MLP, node-per-lane with LDS-resident activation row.
// Accumulators a[64]/c[64]: statically indexed (j-unrolled) -> VGPRs.
// Runtime-indexed operand h[k]/t[k]: LDS (stride 65, conflict-free).
// Weights: lane-uniform -> s_load -> SGPR operand to v_fmac. No scratch.
// Block = 128 thr = 2 waves; wave owns 64 consecutive nodes; in-place safe.
// ---------------------------------------------------------------------------
__global__ __launch_bounds__(128) void mlp_kernel(
    const float* __restrict__ hin,
    const float* __restrict__ W1,   const float* __restrict__ b1,
    const float* __restrict__ gamma,const float* __restrict__ beta,
    const float* __restrict__ mean, const float* __restrict__ var,
    const float* __restrict__ W2,   const float* __restrict__ b2,
    float* __restrict__ xout)
{
    __shared__ float sbuf[2 * 64 * LDSTRIDE];   // 33,280 B

    const int lane = threadIdx.x & 63;
    const int wv   = threadIdx.x >> 6;
    const int gw   = blockIdx.x * 2 + wv;       // global wave = 64-node block
    float* lds = sbuf + wv * (64 * LDSTRIDE);

    const long long base = (long long)gw * 64 * CH;      // float offset
    const long long totF = (long long)N_NODES * CH;

    // ---- stage 64x64 row-block global -> LDS (coalesced float4) ----
    const float4* gin4 = (const float4*)(hin + base);
    for (int i = lane; i < 1024; i += 64) {
        int fo = i * 4;
        float4 v = make_float4(0.f, 0.f, 0.f, 0.f);
        if (base + fo + 3 < totF) v = gin4[i];
        int row = fo >> 6, col = fo & 63;
        float* p = lds + row * LDSTRIDE + col;
        p[0] = v.x; p[1] = v.y; p[2] = v.z; p[3] = v.w;
    }
    __syncthreads();   // staging is cross-lane within the block

    float* myrow = lds + lane * LDSTRIDE;

    // ---- GEMM1: a[j] = b1[j] + sum_k h[k]*W1[k][j] ----
    float a[CH];
    #pragma unroll
    for (int j = 0; j < CH; ++j) a[j] = b1[j];
    for (int k = 0; k < CH; ++k) {              // rolled: hk via LDS read
        float hk = myrow[k];
        const float* wrow = W1 + k * CH;        // lane-uniform -> s_load
        #pragma unroll
        for (int j = 0; j < CH; ++j)
            a[j] = fmaf(hk, wrow[j], a[j]);
    }

    // ---- BN(eval) + ReLU -> own LDS row (no cross-lane, no barrier) ----
    #pragma unroll
    for (int j = 0; j < CH; ++j) {
        float sc = gamma[j] * rsqrtf(var[j] + BN_EPS);
        float sh = beta[j] - mean[j] * sc;
        myrow[j] = fmaxf(fmaf(a[j], sc, sh), 0.0f);
    }

    // ---- GEMM2: c[j] = b2[j] + sum_k t[k]*W2[k][j] ----
    float c[CH];
    #pragma unroll
    for (int j = 0; j < CH; ++j) c[j] = b2[j];
    for (int k = 0; k < CH; ++k) {
        float tk = myrow[k];
        const float* wrow = W2 + k * CH;
        #pragma unroll
        for (int j = 0; j < CH; ++j)
            c[j] = fmaf(tk, wrow[j], c[j]);
    }

    // ---- ReLU -> own LDS row, then coalesced float4 store ----
    #pragma unroll
    for (int j = 0; j < CH; ++j)
        myrow[j] = fmaxf(c[j], 0.0f);
    __syncthreads();   // epilogue store reads other lanes' rows

    float4* gout4 = (float4*)(xout + base);
    for (int i = lane; i < 1024; i += 64) {
        int fo = i * 4;
        if (base + fo + 3 < totF) {
            int row = fo >> 6, col = fo & 63;
            const float* p = lds + row * LDSTRIDE + col;
            gout4[i] = make_float4(p[0], p[1], p[2], p[3]);
        }
    }
}

// ---------------------------------------------------------------------------
// Mean pool: batch is SORTED -> wave-per-graph binary search + direct sum.
// ---------------------------------------------------------------------------
__global__ __launch_bounds__(256) void pool_mean_kernel(
    const float* __restrict__ x, const int* __restrict__ batch,
    float* __restrict__ pooled)
{
    const int lane = threadIdx.x & 63;
    const int g = blockIdx.x * (blockDim.x >> 6) + (threadIdx.x >> 6);
    if (g >= NUM_GRAPHS) return;

    int lo = 0, hi = N_NODES;
    while (lo < hi) { int mid = (lo + hi) >> 1; if (batch[mid] < g) lo = mid + 1; else hi = mid; }
    int start = lo;
    lo = start; hi = N_NODES;
    while (lo < hi) { int mid = (lo + hi) >> 1; if (batch[mid] < g + 1) lo = mid + 1; else hi = mid; }
    int end = lo;

    float s = 0.0f;
    for (int n = start; n < end; ++n) s += x[(size_t)n * CH + lane];
    int c = end - start;
    pooled[(size_t)g * CH + lane] = s / (float)(c > 0 ? c : 1);
}

// ---------------------------------------------------------------------------
// Head: h = relu(pooled@W1+b1); logits = h@W2+b2; softmax(2). Wave per graph.
// ---------------------------------------------------------------------------
__global__ __launch_bounds__(256) void head_kernel(
    const float* __restrict__ pooled,
    const float* __restrict__ W1, const float* __restrict__ b1,
    const float* __restrict__ W2, const float* __restrict__ b2,
    float* __restrict__ out)
{
    __shared__ float w1[CH * CH];
    __shared__ float b1s[CH];
    __shared__ float w2s[CH * 2];

    for (int i = threadIdx.x; i < CH * CH; i += blockDim.x) w1[i] = W1[i];
    if (threadIdx.x < CH)     b1s[threadIdx.x] = b1[threadIdx.x];
    if (threadIdx.x < CH * 2) w2s[threadIdx.x] = W2[threadIdx.x];
    __syncthreads();

    const int lane = threadIdx.x & 63;
    const int g = blockIdx.x * (blockDim.x >> 6) + (threadIdx.x >> 6);
    if (g >= NUM_GRAPHS) return;

    float p = pooled[(size_t)g * CH + lane];

    float acc = b1s[lane];
    #pragma unroll
    for (int k = 0; k < CH; ++k)
        acc = fmaf(__shfl(p, k, 64), w1[k * CH + lane], acc);
    float h = fmaxf(acc, 0.0f);

    float l0 = h * w2s[lane * 2 + 0];
    float l1 = h * w2s[lane * 2 + 1];
    #pragma unroll
    for (int off = 32; off > 0; off >>= 1) {
        l0 += __shfl_xor(l0, off, 64);
        l1 += __shfl_xor(l1, off, 64);
    }
    if (lane == 0) {
        l0 += b2[0];
        l1 += b2[1];
        float m  = fmaxf(l0, l1);
        float e0 = expf(l0 - m), e1 = expf(l1 - m);
        float s  = e0 + e1;
        out[(size_t)g * 2 + 0] = e0 / s;
        out[(size_t)g * 2 + 1] = e1 / s;
    }
}

extern "C" void kernel_launch(void* const* d_in, const int* in_sizes, int n_in,
                              void* d_out, int out_size, void* d_ws, size_t ws_size,
                              hipStream_t stream)
{
    const float* x      = (const float*)d_in[0];
    const int*   ei     = (const int*)  d_in[1];
    const int*   src    = ei;
    const int*   dst    = ei + N_EDGES;
    const int*   batch  = (const int*)  d_in[2];
    const float* convW1 = (const float*)d_in[3];
    const float* convb1 = (const float*)d_in[4];
    const float* gamma  = (const float*)d_in[5];
    const float* beta   = (const float*)d_in[6];
    const float* mean   = (const float*)d_in[7];
    const float* var    = (const float*)d_in[8];
    const float* convW2 = (const float*)d_in[9];
    const float* convb2 = (const float*)d_in[10];
    const float* mlpW1  = (const float*)d_in[11];
    const float* mlpb1  = (const float*)d_in[12];
    const float* mlpW2  = (const float*)d_in[13];
    const float* mlpb2  = (const float*)d_in[14];
    float* out = (float*)d_out;

    // ---- workspace layout ----
    int* deg         = (int*)d_ws;                 // NP
    int* rowptr      = deg + NP;                   // NP
    int* cursor      = rowptr + NP;                // NP
    int* blockSums   = cursor + NP;                // 512
    int* blockPrefix = blockSums + 512;            // 512
    int* eidx        = blockPrefix + 512;          // N_EDGES
    float* xA        = (float*)(eidx + N_EDGES);   // N_NODES*CH
    float* xB        = xA + (size_t)N_NODES * CH;  // N_NODES*CH
    float* pooled    = xB + (size_t)N_NODES * CH;  // NUM_GRAPHS*CH

    // ---- CSR build ----
    hipMemsetAsync(deg, 0, NP * sizeof(int), stream);
    hist_kernel<<<(N_EDGES + 255) / 256, 256, 0, stream>>>(dst, deg);
    scan1_kernel<<<NBLK1, 256, 0, stream>>>(deg, rowptr, blockSums);
    scan2_kernel<<<1, 512, 0, stream>>>(blockSums, blockPrefix);
    scan3_kernel<<<NBLK1, 256, 0, stream>>>(rowptr, cursor, blockPrefix);
    scatter_edges_kernel<<<2048, 256, 0, stream>>>(src, dst, cursor, eidx);

    const int aggGrid = (N_NODES * 16 + 255) / 256;   // 6250 blocks
    const int mlpGrid = (N_NODES + 127) / 128;        // 782 blocks (2 waves each)

    // ---- 3 GIN layers: aggregate (TLP gather) then MLP (in-place) ----
    aggregate_kernel<<<aggGrid, 256, 0, stream>>>(x, rowptr, deg, eidx, xA);
    mlp_kernel<<<mlpGrid, 128, 0, stream>>>(xA,
        convW1, convb1, gamma, beta, mean, var, convW2, convb2, xA);
    aggregate_kernel<<<aggGrid, 256, 0, stream>>>(xA, rowptr, deg, eidx, xB);
    mlp_kernel<<<mlpGrid, 128, 0, stream>>>(xB,
        convW1 + CH*CH, convb1 + CH, gamma + CH, beta + CH, mean + CH, var + CH,
        convW2 + CH*CH, convb2 + CH, xB);
    aggregate_kernel<<<aggGrid, 256, 0, stream>>>(xB, rowptr, deg, eidx, xA);
    mlp_kernel<<<mlpGrid, 128, 0, stream>>>(xA,
        convW1 + 2*CH*CH, convb1 + 2*CH, gamma + 2*CH, beta + 2*CH, mean + 2*CH,
        var + 2*CH, convW2 + 2*CH*CH, convb2 + 2*CH, xA);

    // ---- pool + head ----
    pool_mean_kernel<<<NUM_GRAPHS / 4, 256, 0, stream>>>(xA, batch, pooled);
    head_kernel<<<NUM_GRAPHS / 4, 256, 0, stream>>>(
        pooled, mlpW1, mlpb1, mlpW2, mlpb2, out);
}